// Round 3
// baseline (87.371 us; speedup 1.0000x reference)
//
#include <hip/hip_runtime.h>
#include <math.h>

#define N 512
#define SIGMA 0.5f
#define EPS 1e-7f

typedef __attribute__((ext_vector_type(8))) short bf16x8;
typedef __attribute__((ext_vector_type(4))) float f32x4;

// ---------------------------------------------------------------------------
__device__ __forceinline__ unsigned short f2bf(float x) {
    unsigned int b = __float_as_uint(x);
    b += 0x7FFFu + ((b >> 16) & 1u);   // RNE; inputs finite
    return (unsigned short)(b >> 16);
}

// ---------------------------------------------------------------------------
// Kernel 1 (setup): grid 65 x 512.
//  blocks 0..63 : convert feature fp32->bf16 + row sq-norms (wave w -> row 8b+w)
//  block 64     : rank-sort the 512 labels (exact, stable) + zero out[0]
// ---------------------------------------------------------------------------
__global__ __launch_bounds__(512)
void setup_kernel(const float* __restrict__ feat,
                  const float* __restrict__ label,
                  unsigned short* __restrict__ featb,
                  float* __restrict__ sqn,
                  float* __restrict__ sl, int* __restrict__ sidx,
                  int* __restrict__ ipos, float* __restrict__ out) {
    const int t = threadIdx.x;
    if (blockIdx.x < 64) {
        const int wave = t >> 6, lane = t & 63;
        const int row = blockIdx.x * 8 + wave;
        const float* f = feat + (size_t)row * N;
        unsigned short* fb = featb + (size_t)row * N;
        float s = 0.f;
        #pragma unroll
        for (int sweep = 0; sweep < 2; ++sweep) {
            int c = sweep * 256 + lane * 4;
            float4 v = *(const float4*)(f + c);
            unsigned short b0 = f2bf(v.x), b1 = f2bf(v.y),
                           b2 = f2bf(v.z), b3 = f2bf(v.w);
            *(ushort4*)(fb + c) = make_ushort4(b0, b1, b2, b3);
            float r0 = __uint_as_float((unsigned int)b0 << 16);
            float r1 = __uint_as_float((unsigned int)b1 << 16);
            float r2 = __uint_as_float((unsigned int)b2 << 16);
            float r3 = __uint_as_float((unsigned int)b3 << 16);
            s += r0 * r0 + r1 * r1 + r2 * r2 + r3 * r3;
        }
        #pragma unroll
        for (int off = 32; off > 0; off >>= 1) s += __shfl_down(s, off);
        if (lane == 0) sqn[row] = s;
    } else {
        // ---- exact stable rank-sort of labels ----
        __shared__ __align__(16) float lab[N];
        const float lt = label[t];
        lab[t] = lt;
        if (t == 0) out[0] = 0.f;
        __syncthreads();
        int rank = 0;
        const float4* L4 = (const float4*)lab;
        #pragma unroll 8
        for (int j4 = 0; j4 < N / 4; ++j4) {
            float4 v = L4[j4];
            int j = j4 * 4;
            rank += ((v.x < lt) || (v.x == lt && (j + 0) < t)) ? 1 : 0;
            rank += ((v.y < lt) || (v.y == lt && (j + 1) < t)) ? 1 : 0;
            rank += ((v.z < lt) || (v.z == lt && (j + 2) < t)) ? 1 : 0;
            rank += ((v.w < lt) || (v.w == lt && (j + 3) < t)) ? 1 : 0;
        }
        sl[rank] = lt;    // exact bits, just permuted
        sidx[rank] = t;
        ipos[t] = rank;
    }
}

// ---------------------------------------------------------------------------
// Kernel 2: F matrix via bf16 MFMA Gram. One wave per 16x16 output tile.
// ---------------------------------------------------------------------------
__global__ void fmat_mfma_kernel(const unsigned short* __restrict__ featb,
                                 const float* __restrict__ sqn,
                                 float* __restrict__ Fm) {
    const int r0 = blockIdx.y * 16;
    const int c0 = blockIdx.x * 16;
    const int lane = threadIdx.x;
    const int m = lane & 15;
    const int kb = (lane >> 4) * 8;

    const unsigned short* arow = featb + (size_t)(r0 + m) * N + kb;
    const unsigned short* brow = featb + (size_t)(c0 + m) * N + kb;

    f32x4 acc = {0.f, 0.f, 0.f, 0.f};
    #pragma unroll
    for (int k0 = 0; k0 < N; k0 += 32) {
        bf16x8 a = *(const bf16x8*)(arow + k0);
        bf16x8 b = *(const bf16x8*)(brow + k0);
        acc = __builtin_amdgcn_mfma_f32_16x16x32_bf16(a, b, acc, 0, 0, 0);
    }

    const int col = c0 + (lane & 15);
    const int rowb = r0 + (lane >> 4) * 4;
    const float nc = sqn[col];
    #pragma unroll
    for (int r = 0; r < 4; ++r) {
        const int row = rowb + r;
        float sq = sqn[row] + nc - 2.f * acc[r];
        float v = (row == col) ? 0.f : -SIGMA * sqrtf(fmaxf(sq, 0.f));
        Fm[(size_t)row * N + col] = v;
    }
}

// ---------------------------------------------------------------------------
// Kernel 3: per-row softmax + interval-denom (sorted order) + loss.
// One block (512 threads) per row i. Thread t = orig column k AND sorted
// position p. Row max is exactly 0 (diag F = 0, off-diag < 0) -> no max pass.
// denom[k] = total - sum_{j: d_j < R_k} S_j, the inner set being a contiguous
// interval in label-sorted order (d is V-shaped, monotone per half).
// ---------------------------------------------------------------------------
__global__ __launch_bounds__(512)
void row_kernel(const float* __restrict__ Fm,
                const float* __restrict__ label,
                const float* __restrict__ sl,
                const int* __restrict__ sidx,
                const int* __restrict__ ipos,
                float* __restrict__ out) {
    const int i = blockIdx.x;
    const int t = threadIdx.x;        // 0..511
    const int wave = t >> 6, lane = t & 63;

    __shared__ __align__(16) float ds_[N];  // distance at sorted position
    __shared__ __align__(16) float Ss[N];   // S by orig column
    __shared__ __align__(16) float Ps[N];   // inclusive prefix of sorted S
    __shared__ float red[8];
    __shared__ float wsum[8];

    const float li = label[i];
    const float f = Fm[(size_t)i * N + t];
    const float e = __expf(f);

    // distance at sorted position t (bitwise == reference's R values)
    ds_[t] = fabsf(li - sl[t]);

    // Z = sum_j exp(f_j)  (includes diagonal exp(0)=1)
    float z = e;
    #pragma unroll
    for (int off = 32; off > 0; off >>= 1) z += __shfl_xor(z, off);
    if (lane == 0) red[wave] = z;
    __syncthreads();
    const float Z = red[0] + red[1] + red[2] + red[3] +
                    red[4] + red[5] + red[6] + red[7];
    float S = e / Z;
    if (t == i) S = 0.f;              // exclude j==i everywhere
    Ss[t] = S;
    __syncthreads();

    // gather S into sorted order, block-wide inclusive scan
    float v = Ss[sidx[t]];
    #pragma unroll
    for (int off = 1; off < 64; off <<= 1) {
        float u = __shfl_up(v, off);
        if (lane >= off) v += u;
    }
    if (lane == 63) wsum[wave] = v;
    __syncthreads();
    float base = 0.f;
    #pragma unroll
    for (int w = 0; w < 8; ++w) base += (w < wave) ? wsum[w] : 0.f;
    Ps[t] = base + v;
    __syncthreads();

    const float total = Ps[N - 1];
    const int posi = ipos[i];
    const int pt = ipos[t];
    const float Rk = ds_[pt];         // == fabsf(li - label[t]), exact

    // left half [0, posi]: d non-increasing; first p with d[p] < Rk
    int lo = 0, hi = posi + 1;
    while (lo < hi) { int mid = (lo + hi) >> 1; if (ds_[mid] < Rk) hi = mid; else lo = mid + 1; }
    const int La = lo;                // posi+1 if none
    // right half [posi, N): d non-decreasing; first p with d[p] >= Rk
    lo = posi; hi = N;
    while (lo < hi) { int mid = (lo + hi) >> 1; if (ds_[mid] >= Rk) hi = mid; else lo = mid + 1; }
    const int Rb = lo - 1;            // last p with d < Rk

    const float inner = ((Rb >= 0) ? Ps[Rb] : 0.f) - ((La > 0) ? Ps[La - 1] : 0.f);
    const float denom = total - inner;
    float part = (t == i) ? 0.f : (f - __logf(denom + EPS));

    #pragma unroll
    for (int off = 32; off > 0; off >>= 1) part += __shfl_xor(part, off);
    if (lane == 0) red[wave] = part;
    __syncthreads();
    if (t == 0) {
        float tot = red[0] + red[1] + red[2] + red[3] +
                    red[4] + red[5] + red[6] + red[7];
        atomicAdd(out, tot * (-1.f / ((float)N * (float)(N - 1))));
    }
}

// ---------------------------------------------------------------------------
extern "C" void kernel_launch(void* const* d_in, const int* in_sizes, int n_in,
                              void* d_out, int out_size, void* d_ws, size_t ws_size,
                              hipStream_t stream) {
    const float* feature = (const float*)d_in[0];   // [512, 512] f32
    const float* label   = (const float*)d_in[1];   // [512, 1]  f32
    float* out = (float*)d_out;

    float* Fm             = (float*)d_ws;                          // 1 MB
    unsigned short* featb = (unsigned short*)(Fm + (size_t)N * N); // 512 KB
    float* sqn            = (float*)(featb + (size_t)N * N);       // 2 KB
    float* sl             = sqn + N;                               // 2 KB
    int*   sidx           = (int*)(sl + N);                        // 2 KB
    int*   ipos           = sidx + N;                              // 2 KB

    setup_kernel<<<65, 512, 0, stream>>>(feature, label, featb, sqn,
                                         sl, sidx, ipos, out);
    {
        dim3 grid(N / 16, N / 16);
        fmat_mfma_kernel<<<grid, 64, 0, stream>>>(featb, sqn, Fm);
    }
    row_kernel<<<N, N, 0, stream>>>(Fm, label, sl, sidx, ipos, out);
}